// Round 14
// baseline (1034.187 us; speedup 1.0000x reference)
//
#include <hip/hip_runtime.h>

typedef unsigned int u32;
typedef _Float16 f16;
typedef __attribute__((ext_vector_type(8))) _Float16 f16x8;
typedef __attribute__((ext_vector_type(4))) _Float16 f16x4;
typedef __attribute__((ext_vector_type(4))) float f32x4;

#define NNODES 100000
#define NEDGES 600000
#define CC 16
#define HH 48
#define NL 5

// ---- ws layout (float units), total 4,000,064 floats = 16.0 MB ----
// x1 region: xh1 (f16, 800k floats) @ OX1 ; nfh (f16, 800k floats) @ OX1+800000
// x2 region: xh2 (f16, 800k floats) @ OX2
#define OX1   0
#define ONFH  800000
#define OX2   1600000
#define OROW  3200000
#define ODEG  3300032          // deg during CSR build; ALIASED as W-frag pane after
#define OGF   3300032
#define OPERM 3400032
#define OSL   4000032
#define WS_CSR_FLOATS    4000064

// =================== CSR build ===================
__global__ __launch_bounds__(256) void count_deg(const int* __restrict__ ei, int* __restrict__ deg){
  int e = blockIdx.x * 256 + threadIdx.x;
  if (e >= NEDGES) return;
  atomicAdd(&deg[ei[NEDGES + e]], 1);
}

__global__ __launch_bounds__(1024) void scan_deg(const int* __restrict__ deg, int* __restrict__ rowptr){
  __shared__ int part[1024];
  int t = threadIdx.x;
  const int CH = (NNODES + 1023) / 1024;
  int b = t * CH;
  int e = b + CH < NNODES ? b + CH : NNODES;
  int s = 0;
  for (int i = b; i < e; i++) s += deg[i];
  part[t] = s;
  __syncthreads();
  for (int off = 1; off < 1024; off <<= 1){
    int v = (t >= off) ? part[t - off] : 0;
    __syncthreads();
    part[t] += v;
    __syncthreads();
  }
  int run = (t == 0) ? 0 : part[t - 1];
  for (int i = b; i < e; i++){ rowptr[i] = run; run += deg[i]; }
  if (t == 1023) rowptr[NNODES] = run;
}

__global__ __launch_bounds__(256) void scatter_perm(const int* __restrict__ ei,
    const int* __restrict__ rowptr, int* __restrict__ deg2, int* __restrict__ perm){
  int e = blockIdx.x * 256 + threadIdx.x;
  if (e >= NEDGES) return;
  int d = ei[NEDGES + e];
  int pos = rowptr[d] + atomicAdd(&deg2[d], 1);
  perm[pos] = e;
}

// =================== fp32 -> f16 convert (4 elems/thread) ===================
__global__ __launch_bounds__(256) void cvt_f16(const float* __restrict__ src, f16* __restrict__ dst, int n4){
  int i = blockIdx.x * 256 + threadIdx.x;
  if (i >= n4) return;
  float4 v = ((const float4*)src)[i];
  f16x4 h; h[0]=(f16)v.x; h[1]=(f16)v.y; h[2]=(f16)v.z; h[3]=(f16)v.w;
  *(f16x4*)&dst[i*4] = h;
}

// ============ W-fragment precompute (unchanged from r13, proven) ============
__global__ __launch_bounds__(256) void prep_wfrag(
    const float* __restrict__ e1w0, const float* __restrict__ e1wh, const float* __restrict__ e1wc,
    const float* __restrict__ e2w0, const float* __restrict__ e2wh, f16* __restrict__ gf)
{
  int idx = blockIdx.x * 256 + threadIdx.x;
  if (idx >= 39936) return;
  int j = idx & 7, lane = (idx >> 3) & 63, f = idx >> 9;
  int wt = f % 3, ksl = f / 3;
  int ks = ksl & 1, lay = ksl >> 1;
  int k = ks * 32 + ((lane >> 4) << 3) + j;
  int m = wt * 16 + (lane & 15);
  const float* w; int Kl;
  if (lay == 0){ w = e1w0; Kl = 32; }
  else if (lay <= 5){ w = e1wh + (lay - 1) * 2304; Kl = 48; }
  else if (lay == 6){ w = e1wc; Kl = 48; }
  else if (lay == 7){ w = e2w0; Kl = 32; }
  else { w = e2wh + (lay - 8) * 2304; Kl = 48; }
  gf[idx] = (k < Kl) ? (f16)w[k * 48 + m] : (f16)0.f;
}

// ====== NodeConv: f16 node features in/out, fp32 math, CSR node-parallel x4 ======
__global__ __launch_bounds__(256) void nc_csr4h(
    const f16* __restrict__ xh, const int* __restrict__ ei,
    const float* __restrict__ ang,
    const int* __restrict__ rowptr, const int* __restrict__ perm,
    const float* __restrict__ w0, const float* __restrict__ b0,
    const float* __restrict__ wh, const float* __restrict__ bh,
    f16* __restrict__ xout)
{
  int tid = blockIdx.x * 256 + threadIdx.x;
  int n = tid >> 2, j = tid & 3;
  if (n >= NNODES) return;
  int beg = rowptr[n], end = rowptr[n + 1];

  float xd[16];
  {
    f16x8 r0 = *(const f16x8*)&xh[n * 16];
    f16x8 r1 = *(const f16x8*)&xh[n * 16 + 8];
    #pragma unroll
    for (int i = 0; i < 8; i++){ xd[i] = (float)r0[i]; xd[8 + i] = (float)r1[i]; }
  }
  float p0[16];
  #pragma unroll
  for (int jj = 0; jj < 16; jj++) p0[jj] = b0[jj];
  #pragma unroll
  for (int k = 0; k < 16; k++){
    float v = xd[k];
    #pragma unroll
    for (int jj = 0; jj < 16; jj++) p0[jj] = fmaf(v, w0[k*16 + jj], p0[jj]);
  }

  float sum[16];
  #pragma unroll
  for (int jj = 0; jj < 16; jj++) sum[jj] = 0.f;

  for (int idx = beg + j; idx < end; idx += 4){
    int e = perm[idx];
    int s = ei[e];
    float a_ = ang[e];
    float xs[16];
    {
      f16x8 r0 = *(const f16x8*)&xh[(long)s * 16];
      f16x8 r1 = *(const f16x8*)&xh[(long)s * 16 + 8];
      #pragma unroll
      for (int i = 0; i < 8; i++){ xs[i] = (float)r0[i]; xs[8 + i] = (float)r1[i]; }
    }
    float acc[16], h[16];
    #pragma unroll
    for (int jj = 0; jj < 16; jj++) acc[jj] = p0[jj];
    #pragma unroll
    for (int k = 0; k < 16; k++){
      float v = xs[k];
      #pragma unroll
      for (int jj = 0; jj < 16; jj++) acc[jj] = fmaf(v, w0[(16 + k)*16 + jj], acc[jj]);
    }
    #pragma unroll
    for (int jj = 0; jj < 16; jj++) h[jj] = fmaxf(fmaf(a_, w0[32*16 + jj], acc[jj]), 0.f);

    for (int l = 0; l < NL; l++){
      const float* w = wh + l * 256;
      const float* b = bh + l * 16;
      #pragma unroll
      for (int jj = 0; jj < 16; jj++) acc[jj] = b[jj];
      #pragma unroll
      for (int k = 0; k < 16; k++){
        float v = h[k];
        #pragma unroll
        for (int jj = 0; jj < 16; jj++) acc[jj] = fmaf(v, w[k*16 + jj], acc[jj]);
      }
      #pragma unroll
      for (int jj = 0; jj < 16; jj++) h[jj] = fmaxf(acc[jj], 0.f);
    }
    #pragma unroll
    for (int jj = 0; jj < 16; jj++) sum[jj] += h[jj];
  }

  #pragma unroll
  for (int jj = 0; jj < 16; jj++){
    sum[jj] += __shfl_xor(sum[jj], 1);
    sum[jj] += __shfl_xor(sum[jj], 2);
  }
  if (j == 0){
    float inv = 1.f / fmaxf((float)(end - beg), 1.f);
    f16x8 o0, o1;
    #pragma unroll
    for (int i = 0; i < 8; i++){ o0[i] = (f16)(sum[i]*inv); o1[i] = (f16)(sum[8+i]*inv); }
    *(f16x8*)&xout[n * 16]     = o0;
    *(f16x8*)&xout[n * 16 + 8] = o1;
  }
}

// ============================================================================
// Fused EdgeConv1+EdgeConv2 v4: perm-ordered (dst-sorted) edges, f16 node gathers,
// both convs staged upfront -> ONE barrier. W-frags from global (L2-broadcast).
// LDS = Hb[2] = 32768 B. A=W (m=channel), B=H (n=edge); D[row=4q+reg]=channel,
// D[col=lane&15]=edge-in-wave. H swizzle: (row,k) -> row*64 + ((k/8 ^ row%8)*8 | k%8).
// ============================================================================
__global__ __launch_bounds__(256) void ec_mfma(
    const f16* __restrict__ xh1, const f16* __restrict__ xh2,
    const int* __restrict__ ei, const float* __restrict__ act,
    const int* __restrict__ perm, const f16* __restrict__ gf,
    const float* __restrict__ e1wc, const float* __restrict__ e1b0,
    const float* __restrict__ e1bh, const float* __restrict__ e1bc,
    const float* __restrict__ e2b0, const float* __restrict__ e2bh,
    const float* __restrict__ e2wc, const float* __restrict__ e2bc,
    float* __restrict__ out, float* __restrict__ slacc)
{
  __shared__ __align__(16) f16 Hb[2][128 * 64];   // 32768 B

  const int t = threadIdx.x;
  const int lane = t & 63;
  const int wv = t >> 6;
  const int q = lane >> 4, n15 = lane & 15;
  const int ebase = blockIdx.x * 64;

  const int peL = perm[ebase + wv * 16 + n15];    // this lane's edge (original id)
  const float aL = act[peL];
  const float bc2v = e2bc[0];
  float4 wc1r[3], wcA[3], wcB[3];
  #pragma unroll
  for (int wt = 0; wt < 3; wt++){
    wc1r[wt] = *(const float4*)&e1wc[2304 + wt*16 + 4*q];
    wcA[wt]  = *(const float4*)&e2wc[wt*16 + 4*q];
    wcB[wt]  = *(const float4*)&e2wc[48 + wt*16 + 4*q];
  }

  // ---- stage BOTH convs' H rows (2 threads/row; this thread's node = 2 chunks) ----
  {
    int row = t >> 1, half = t & 1;
    int pe = perm[ebase + (row & 63)];
    int s = ei[pe], dn = ei[NEDGES + pe];
    int node = ((half ^ (row >> 6)) & 1) ? s : dn;  // f1=[x_d|x_s], f2=[x_s|x_d]
    int rs = row & 7;
    f16x8 a0 = *(const f16x8*)&xh1[(long)node * 16];
    f16x8 a1 = *(const f16x8*)&xh1[(long)node * 16 + 8];
    f16* hp = &Hb[0][row << 6];
    *(f16x8*)&hp[((2*half)     ^ rs) << 3] = a0;
    *(f16x8*)&hp[((2*half + 1) ^ rs) << 3] = a1;
    f16x8 b0v = *(const f16x8*)&xh2[(long)node * 16];
    f16x8 b1v = *(const f16x8*)&xh2[(long)node * 16 + 8];
    f16* hq = &Hb[1][row << 6];
    *(f16x8*)&hq[((2*half)     ^ rs) << 3] = b0v;
    *(f16x8*)&hq[((2*half + 1) ^ rs) << 3] = b1v;
    if (half){
      f16x8 z = {};
      *(f16x8*)&hp[(6 ^ rs) << 3] = z; *(f16x8*)&hp[(7 ^ rs) << 3] = z;
      *(f16x8*)&hq[(6 ^ rs) << 3] = z; *(f16x8*)&hq[(7 ^ rs) << 3] = z;
    }
  }
  __syncthreads();   // the ONLY barrier

  float ef[3][4];
  float side = 0.f;
  float outAcc = 0.f;

  // mode 0: hidden(relu->H). 1: EC1-final(relu,fe+side->H f1 rows).
  // 2: combine(no relu, ef=C+act*wc1r). 3: EC2-final(relu,fe2+side,out dot).
  auto layer = [&](f16* H, int lay, const float* bias, int nks, int mode){
    const int nEt = (mode == 2) ? 1 : 2;
    f32x4 C[3][2];
    #pragma unroll
    for (int wt = 0; wt < 3; wt++){
      float4 b4 = *(const float4*)&bias[wt*16 + 4*q];
      C[wt][0] = (f32x4){b4.x, b4.y, b4.z, b4.w};
      C[wt][1] = C[wt][0];
    }
    for (int ks = 0; ks < nks; ks++){
      int c = ks*4 + q;
      f16x8 Af[3];
      #pragma unroll
      for (int wt = 0; wt < 3; wt++)
        Af[wt] = *(const f16x8*)&gf[((((lay*2 + ks)*3) + wt) << 9) + (lane << 3)];
      for (int et = 0; et < nEt; et++){
        int r = (et << 6) + wv*16 + n15;
        f16x8 Bf = *(const f16x8*)&H[(r << 6) + ((c ^ (r & 7)) << 3)];
        #pragma unroll
        for (int wt = 0; wt < 3; wt++)
          C[wt][et] = __builtin_amdgcn_mfma_f32_16x16x32_f16(Af[wt], Bf, C[wt][et], 0, 0, 0);
      }
    }
    if (mode == 0){
      #pragma unroll
      for (int et = 0; et < 2; et++){
        int r = (et << 6) + wv*16 + n15;
        #pragma unroll
        for (int wt = 0; wt < 3; wt++){
          f16x4 pk;
          #pragma unroll
          for (int reg = 0; reg < 4; reg++) pk[reg] = (f16)fmaxf(C[wt][et][reg], 0.f);
          int col = wt*16 + 4*q;
          *(f16x4*)&H[(r << 6) + ((((col >> 3) ^ (r & 7)) << 3) | (col & 7))] = pk;
        }
      }
    } else if (mode == 1){
      int r = wv*16 + n15;
      #pragma unroll
      for (int wt = 0; wt < 3; wt++){
        f16x4 pk;
        #pragma unroll
        for (int reg = 0; reg < 4; reg++){
          float v1 = fmaxf(C[wt][0][reg], 0.f);
          float v2 = fmaxf(C[wt][1][reg], 0.f);
          float dd = v1 - v2; side += dd * dd;
          pk[reg] = (f16)(0.5f * (v1 + v2));
        }
        int col = wt*16 + 4*q;
        *(f16x4*)&H[(r << 6) + ((((col >> 3) ^ (r & 7)) << 3) | (col & 7))] = pk;
      }
    } else if (mode == 2){
      #pragma unroll
      for (int wt = 0; wt < 3; wt++){
        float wa[4] = {wc1r[wt].x, wc1r[wt].y, wc1r[wt].z, wc1r[wt].w};
        #pragma unroll
        for (int reg = 0; reg < 4; reg++)
          ef[wt][reg] = C[wt][0][reg] + aL * wa[reg];
      }
    } else {
      #pragma unroll
      for (int wt = 0; wt < 3; wt++){
        float av[4] = {wcA[wt].x, wcA[wt].y, wcA[wt].z, wcA[wt].w};
        float bv[4] = {wcB[wt].x, wcB[wt].y, wcB[wt].z, wcB[wt].w};
        #pragma unroll
        for (int reg = 0; reg < 4; reg++){
          float v1 = fmaxf(C[wt][0][reg], 0.f);
          float v2 = fmaxf(C[wt][1][reg], 0.f);
          float dd = v1 - v2; side += dd * dd;
          float fe = 0.5f * (v1 + v2);
          outAcc += fe * av[reg] + ef[wt][reg] * bv[reg];
        }
      }
    }
  };

  // ================= EdgeConv1 (Hb[0]) =================
  layer(Hb[0], 0, e1b0, 1, 0);
  layer(Hb[0], 1, e1bh + 0*48, 2, 0);
  layer(Hb[0], 2, e1bh + 1*48, 2, 0);
  layer(Hb[0], 3, e1bh + 2*48, 2, 0);
  layer(Hb[0], 4, e1bh + 3*48, 2, 0);
  layer(Hb[0], 5, e1bh + 4*48, 2, 1);
  layer(Hb[0], 6, e1bc, 2, 2);

  // ================= EdgeConv2 (Hb[1], staged pre-barrier) =================
  layer(Hb[1], 7,  e2b0, 1, 0);
  layer(Hb[1], 8,  e2bh + 0*48, 2, 0);
  layer(Hb[1], 9,  e2bh + 1*48, 2, 0);
  layer(Hb[1], 10, e2bh + 2*48, 2, 0);
  layer(Hb[1], 11, e2bh + 3*48, 2, 0);
  layer(Hb[1], 12, e2bh + 4*48, 2, 3);

  // ================= epilogue =================
  outAcc += __shfl_xor(outAcc, 16);
  outAcc += __shfl_xor(outAcc, 32);
  if (lane < 16) out[peL] = outAcc + bc2v;

  float sv = side;
  #pragma unroll
  for (int off = 32; off; off >>= 1) sv += __shfl_down(sv, off);
  if (lane == 0) atomicAdd(slacc, sv);
}

// each (edge,channel) counted once per conv: loss = S/(2*48*E)
__global__ void fin_sl(const float* __restrict__ slacc, float* __restrict__ out){
  if (threadIdx.x == 0 && blockIdx.x == 0)
    out[NEDGES] = slacc[0] * (1.0f / 57600000.0f);
}

// ================= launch ==================
extern "C" void kernel_launch(void* const* d_in, const int* in_sizes, int n_in,
                              void* d_out, int out_size, void* d_ws, size_t ws_size,
                              hipStream_t stream)
{
  if (n_in < 25) return;
  if (ws_size < (size_t)WS_CSR_FLOATS * sizeof(float)) return;  // ws >= 16MB measured r8-r13

  const float* nf  = (const float*)d_in[0];
  const int*   ei  = (const int*)d_in[1];
  const float* ang = (const float*)d_in[2];
  const float* act = (const float*)d_in[4];
  const float* nc1_w0 = (const float*)d_in[5];
  const float* nc1_b0 = (const float*)d_in[6];
  const float* nc1_wh = (const float*)d_in[7];
  const float* nc1_bh = (const float*)d_in[8];
  const float* nc2_w0 = (const float*)d_in[9];
  const float* nc2_b0 = (const float*)d_in[10];
  const float* nc2_wh = (const float*)d_in[11];
  const float* nc2_bh = (const float*)d_in[12];
  const float* e1w0 = (const float*)d_in[13];
  const float* e1b0 = (const float*)d_in[14];
  const float* e1wh = (const float*)d_in[15];
  const float* e1bh = (const float*)d_in[16];
  const float* e1wc = (const float*)d_in[17];
  const float* e1bc = (const float*)d_in[18];
  const float* e2w0 = (const float*)d_in[19];
  const float* e2b0 = (const float*)d_in[20];
  const float* e2wh = (const float*)d_in[21];
  const float* e2bh = (const float*)d_in[22];
  const float* e2wc = (const float*)d_in[23];
  const float* e2bc = (const float*)d_in[24];

  float* ws  = (float*)d_ws;
  float* out = (float*)d_out;

  f16* xh1 = (f16*)(ws + OX1);
  f16* nfh = (f16*)(ws + ONFH);
  f16* xh2 = (f16*)(ws + OX2);
  int* rowptr = (int*)(ws + OROW);
  int* deg    = (int*)(ws + ODEG);
  int* perm   = (int*)(ws + OPERM);
  f16* gf     = (f16*)(ws + OGF);     // aliases deg (dead after scatter_perm)
  float* sl   = ws + OSL;

  const int eb  = (NEDGES + 255) / 256;        // 2344
  const int ecb = NEDGES / 64;                 // 9375 exact
  const int nb4 = (NNODES * 4 + 255) / 256;    // 1563
  const int pfb = (39936 + 255) / 256;         // 156
  const int cvb = (400000 + 255) / 256;        // 1563 (1.6M floats / 4)

  (void)hipMemsetAsync(deg, 0, (size_t)NNODES * sizeof(int), stream);
  (void)hipMemsetAsync(sl, 0, sizeof(float), stream);

  // nf -> f16 (independent of CSR build)
  hipLaunchKernelGGL(cvt_f16, dim3(cvb), dim3(256), 0, stream, nf, nfh, 400000);

  hipLaunchKernelGGL(count_deg, dim3(eb), dim3(256), 0, stream, ei, deg);
  hipLaunchKernelGGL(scan_deg, dim3(1), dim3(1024), 0, stream, deg, rowptr);
  (void)hipMemsetAsync(deg, 0, (size_t)NNODES * sizeof(int), stream);
  hipLaunchKernelGGL(scatter_perm, dim3(eb), dim3(256), 0, stream, ei, rowptr, deg, perm);

  // deg dead: overwrite with W fragments
  hipLaunchKernelGGL(prep_wfrag, dim3(pfb), dim3(256), 0, stream,
      e1w0, e1wh, e1wc, e2w0, e2wh, gf);

  hipLaunchKernelGGL(nc_csr4h, dim3(nb4), dim3(256), 0, stream,
      nfh, ei, ang, rowptr, perm, nc1_w0, nc1_b0, nc1_wh, nc1_bh, xh1);
  hipLaunchKernelGGL(nc_csr4h, dim3(nb4), dim3(256), 0, stream,
      xh1, ei, ang, rowptr, perm, nc2_w0, nc2_b0, nc2_wh, nc2_bh, xh2);

  hipLaunchKernelGGL(ec_mfma, dim3(ecb), dim3(256), 0, stream,
      xh1, xh2, ei, act, perm, gf,
      e1wc, e1b0, e1bh, e1bc, e2b0, e2bh, e2wc, e2bc,
      out, sl);
  hipLaunchKernelGGL(fin_sl, dim3(1), dim3(64), 0, stream, sl, out);
}

// Round 15
// 931.344 us; speedup vs baseline: 1.1104x; 1.1104x over previous
//
#include <hip/hip_runtime.h>

typedef unsigned int u32;
typedef _Float16 f16;
typedef __attribute__((ext_vector_type(8))) _Float16 f16x8;
typedef __attribute__((ext_vector_type(4))) _Float16 f16x4;
typedef __attribute__((ext_vector_type(4))) float f32x4;

#define NNODES 100000
#define NEDGES 600000
#define CC 16
#define HH 48
#define NL 5
#define ECT 5                      // tiles of 64 edges per ec block
#define ECNB 1875                  // 1875 * 5 * 64 = 600000 exact

// ---- ws layout (float units), total 4,000,064 floats = 16.0 MB ----
#define OX1   0                    // xh1 f16 [0, 800000)
#define ONFH  800000               // nfh f16 until nc1; then actp (float 600k)
#define OX2   1600000              // xh2 f16 [1600000, 2400000)
#define OOUTP 2400000              // outp float 600k [2400000, 3000000)
#define OROW  3200000
#define ODEG  3300032              // deg during CSR build; then gf (f16 39936)
#define OGF   3300032
#define OPERM 3400032
#define OSL   4000032
#define WS_NEED_FLOATS 4000064

// =================== CSR build ===================
__global__ __launch_bounds__(256) void count_deg(const int* __restrict__ ei, int* __restrict__ deg){
  int e = blockIdx.x * 256 + threadIdx.x;
  if (e >= NEDGES) return;
  atomicAdd(&deg[ei[NEDGES + e]], 1);
}

__global__ __launch_bounds__(1024) void scan_deg(const int* __restrict__ deg, int* __restrict__ rowptr){
  __shared__ int part[1024];
  int t = threadIdx.x;
  const int CH = (NNODES + 1023) / 1024;
  int b = t * CH;
  int e = b + CH < NNODES ? b + CH : NNODES;
  int s = 0;
  for (int i = b; i < e; i++) s += deg[i];
  part[t] = s;
  __syncthreads();
  for (int off = 1; off < 1024; off <<= 1){
    int v = (t >= off) ? part[t - off] : 0;
    __syncthreads();
    part[t] += v;
    __syncthreads();
  }
  int run = (t == 0) ? 0 : part[t - 1];
  for (int i = b; i < e; i++){ rowptr[i] = run; run += deg[i]; }
  if (t == 1023) rowptr[NNODES] = run;
}

__global__ __launch_bounds__(256) void scatter_perm(const int* __restrict__ ei,
    const int* __restrict__ rowptr, int* __restrict__ deg2, int* __restrict__ perm){
  int e = blockIdx.x * 256 + threadIdx.x;
  if (e >= NEDGES) return;
  int d = ei[NEDGES + e];
  int pos = rowptr[d] + atomicAdd(&deg2[d], 1);
  perm[pos] = e;
}

// =================== fp32 -> f16 convert ===================
__global__ __launch_bounds__(256) void cvt_f16(const float* __restrict__ src, f16* __restrict__ dst, int n4){
  int i = blockIdx.x * 256 + threadIdx.x;
  if (i >= n4) return;
  float4 v = ((const float4*)src)[i];
  f16x4 h; h[0]=(f16)v.x; h[1]=(f16)v.y; h[2]=(f16)v.z; h[3]=(f16)v.w;
  *(f16x4*)&dst[i*4] = h;
}

// =================== act pre-gather / out scatter (streaming) ===================
__global__ __launch_bounds__(256) void gather_act(const float* __restrict__ act,
    const int* __restrict__ perm, float* __restrict__ actp){
  int i = blockIdx.x * 256 + threadIdx.x;
  if (i >= NEDGES) return;
  actp[i] = act[perm[i]];
}

__global__ __launch_bounds__(256) void scatter_out(const float* __restrict__ outp,
    const int* __restrict__ perm, float* __restrict__ out){
  int i = blockIdx.x * 256 + threadIdx.x;
  if (i >= NEDGES) return;
  out[perm[i]] = outp[i];
}

// ============ W-fragment precompute (r13-proven) ============
__global__ __launch_bounds__(256) void prep_wfrag(
    const float* __restrict__ e1w0, const float* __restrict__ e1wh, const float* __restrict__ e1wc,
    const float* __restrict__ e2w0, const float* __restrict__ e2wh, f16* __restrict__ gf)
{
  int idx = blockIdx.x * 256 + threadIdx.x;
  if (idx >= 39936) return;
  int j = idx & 7, lane = (idx >> 3) & 63, f = idx >> 9;
  int wt = f % 3, ksl = f / 3;
  int ks = ksl & 1, lay = ksl >> 1;
  int k = ks * 32 + ((lane >> 4) << 3) + j;
  int m = wt * 16 + (lane & 15);
  const float* w; int Kl;
  if (lay == 0){ w = e1w0; Kl = 32; }
  else if (lay <= 5){ w = e1wh + (lay - 1) * 2304; Kl = 48; }
  else if (lay == 6){ w = e1wc; Kl = 48; }
  else if (lay == 7){ w = e2w0; Kl = 32; }
  else { w = e2wh + (lay - 8) * 2304; Kl = 48; }
  gf[idx] = (k < Kl) ? (f16)w[k * 48 + m] : (f16)0.f;
}

// ====== NodeConv: f16 in/out, fp32 math, 8 threads/node (3-level shfl reduce) ======
__global__ __launch_bounds__(256) void nc_csr8h(
    const f16* __restrict__ xh, const int* __restrict__ ei,
    const float* __restrict__ ang,
    const int* __restrict__ rowptr, const int* __restrict__ perm,
    const float* __restrict__ w0, const float* __restrict__ b0,
    const float* __restrict__ wh, const float* __restrict__ bh,
    f16* __restrict__ xout)
{
  int tid = blockIdx.x * 256 + threadIdx.x;
  int n = tid >> 3, j = tid & 7;
  if (n >= NNODES) return;
  int beg = rowptr[n], end = rowptr[n + 1];

  float xd[16];
  {
    f16x8 r0 = *(const f16x8*)&xh[n * 16];
    f16x8 r1 = *(const f16x8*)&xh[n * 16 + 8];
    #pragma unroll
    for (int i = 0; i < 8; i++){ xd[i] = (float)r0[i]; xd[8 + i] = (float)r1[i]; }
  }
  float p0[16];
  #pragma unroll
  for (int jj = 0; jj < 16; jj++) p0[jj] = b0[jj];
  #pragma unroll
  for (int k = 0; k < 16; k++){
    float v = xd[k];
    #pragma unroll
    for (int jj = 0; jj < 16; jj++) p0[jj] = fmaf(v, w0[k*16 + jj], p0[jj]);
  }

  float sum[16];
  #pragma unroll
  for (int jj = 0; jj < 16; jj++) sum[jj] = 0.f;

  for (int idx = beg + j; idx < end; idx += 8){
    int e = perm[idx];
    int s = ei[e];
    float a_ = ang[e];
    float xs[16];
    {
      f16x8 r0 = *(const f16x8*)&xh[(long)s * 16];
      f16x8 r1 = *(const f16x8*)&xh[(long)s * 16 + 8];
      #pragma unroll
      for (int i = 0; i < 8; i++){ xs[i] = (float)r0[i]; xs[8 + i] = (float)r1[i]; }
    }
    float acc[16], h[16];
    #pragma unroll
    for (int jj = 0; jj < 16; jj++) acc[jj] = p0[jj];
    #pragma unroll
    for (int k = 0; k < 16; k++){
      float v = xs[k];
      #pragma unroll
      for (int jj = 0; jj < 16; jj++) acc[jj] = fmaf(v, w0[(16 + k)*16 + jj], acc[jj]);
    }
    #pragma unroll
    for (int jj = 0; jj < 16; jj++) h[jj] = fmaxf(fmaf(a_, w0[32*16 + jj], acc[jj]), 0.f);

    for (int l = 0; l < NL; l++){
      const float* w = wh + l * 256;
      const float* b = bh + l * 16;
      #pragma unroll
      for (int jj = 0; jj < 16; jj++) acc[jj] = b[jj];
      #pragma unroll
      for (int k = 0; k < 16; k++){
        float v = h[k];
        #pragma unroll
        for (int jj = 0; jj < 16; jj++) acc[jj] = fmaf(v, w[k*16 + jj], acc[jj]);
      }
      #pragma unroll
      for (int jj = 0; jj < 16; jj++) h[jj] = fmaxf(acc[jj], 0.f);
    }
    #pragma unroll
    for (int jj = 0; jj < 16; jj++) sum[jj] += h[jj];
  }

  #pragma unroll
  for (int jj = 0; jj < 16; jj++){
    sum[jj] += __shfl_xor(sum[jj], 1);
    sum[jj] += __shfl_xor(sum[jj], 2);
    sum[jj] += __shfl_xor(sum[jj], 4);
  }
  if (j == 0){
    float inv = 1.f / fmaxf((float)(end - beg), 1.f);
    f16x8 o0, o1;
    #pragma unroll
    for (int i = 0; i < 8; i++){ o0[i] = (f16)(sum[i]*inv); o1[i] = (f16)(sum[8+i]*inv); }
    *(f16x8*)&xout[n * 16]     = o0;
    *(f16x8*)&xout[n * 16 + 8] = o1;
  }
}

// ============================================================================
// Fused EdgeConv1+EdgeConv2 v5: software-pipelined. 1875 blocks x 5 tiles x 64 edges.
// Steps = tile*2+conv; H double-buffered (2 x 16KB). Node ids for all tiles
// precomputed in prologue; next step's xh gathers issue before compute, store
// after -> gather latency overlaps a full conv pass. One barrier per step.
// A=W-frags from global (L2-broadcast); D[row=4q+reg]=channel, D[col]=edge.
// H swizzle (proven): (row,k) -> row*64 + ((k/8 ^ row%8)*8 | k%8).
// actp sequential reads; outp sequential writes (descattered).
// ============================================================================
__global__ __launch_bounds__(256) void ec_mfma(
    const f16* __restrict__ xh1, const f16* __restrict__ xh2,
    const int* __restrict__ ei, const int* __restrict__ perm,
    const float* __restrict__ actp, const f16* __restrict__ gf,
    const float* __restrict__ e1wc, const float* __restrict__ e1b0,
    const float* __restrict__ e1bh, const float* __restrict__ e1bc,
    const float* __restrict__ e2b0, const float* __restrict__ e2bh,
    const float* __restrict__ e2wc, const float* __restrict__ e2bc,
    float* __restrict__ outp, float* __restrict__ slacc)
{
  __shared__ __align__(16) f16 Hb[2][128 * 64];   // 32768 B

  const int t = threadIdx.x;
  const int lane = t & 63;
  const int wv = t >> 6;
  const int q = lane >> 4, n15 = lane & 15;
  const int row = t >> 1, half = t & 1;
  const int gebase = blockIdx.x * (ECT * 64);

  const float bc2v = e2bc[0];
  float4 wc1r[3], wcA[3], wcB[3];
  #pragma unroll
  for (int wt = 0; wt < 3; wt++){
    wc1r[wt] = *(const float4*)&e1wc[2304 + wt*16 + 4*q];
    wcA[wt]  = *(const float4*)&e2wc[wt*16 + 4*q];
    wcB[wt]  = *(const float4*)&e2wc[48 + wt*16 + 4*q];
  }

  // ---- prologue: node ids for all tiles (this thread stages row `row`) ----
  int node[ECT];
  #pragma unroll
  for (int tt = 0; tt < ECT; tt++){
    int pe = perm[gebase + tt * 64 + (row & 63)];
    int s = ei[pe], dn = ei[NEDGES + pe];
    node[tt] = ((half ^ (row >> 6)) & 1) ? s : dn;   // f1=[x_d|x_s], f2=[x_s|x_d]
  }

  f16x8 pa0, pa1;                  // prefetched H data for the upcoming step
  const int rs = row & 7;
  auto store_lds = [&](f16* H){
    f16* hp = &H[row << 6];
    *(f16x8*)&hp[((2*half)     ^ rs) << 3] = pa0;
    *(f16x8*)&hp[((2*half + 1) ^ rs) << 3] = pa1;
    if (half){
      f16x8 z = {};
      *(f16x8*)&hp[(6 ^ rs) << 3] = z;
      *(f16x8*)&hp[(7 ^ rs) << 3] = z;
    }
  };

  float ef[3][4];
  float side = 0.f;

  // one layer on H. mode 0: hidden(relu->H). 1: EC1-final(relu,fe+side->f1 rows).
  // 2: combine(no relu, ef=C+act*wc1r). 3: EC2-final(relu,fe2+side,outAcc dot).
  float outAcc = 0.f;
  float aL = 0.f;
  auto layer = [&](f16* H, int lay, const float* bias, int nks, int mode){
    const int nEt = (mode == 2) ? 1 : 2;
    f32x4 C[3][2];
    #pragma unroll
    for (int wt = 0; wt < 3; wt++){
      float4 b4 = *(const float4*)&bias[wt*16 + 4*q];
      C[wt][0] = (f32x4){b4.x, b4.y, b4.z, b4.w};
      C[wt][1] = C[wt][0];
    }
    for (int ks = 0; ks < nks; ks++){
      int c = ks*4 + q;
      f16x8 Af[3];
      #pragma unroll
      for (int wt = 0; wt < 3; wt++)
        Af[wt] = *(const f16x8*)&gf[((((lay*2 + ks)*3) + wt) << 9) + (lane << 3)];
      for (int et = 0; et < nEt; et++){
        int r = (et << 6) + wv*16 + n15;
        f16x8 Bf = *(const f16x8*)&H[(r << 6) + ((c ^ (r & 7)) << 3)];
        #pragma unroll
        for (int wt = 0; wt < 3; wt++)
          C[wt][et] = __builtin_amdgcn_mfma_f32_16x16x32_f16(Af[wt], Bf, C[wt][et], 0, 0, 0);
      }
    }
    if (mode == 0){
      #pragma unroll
      for (int et = 0; et < 2; et++){
        int r = (et << 6) + wv*16 + n15;
        #pragma unroll
        for (int wt = 0; wt < 3; wt++){
          f16x4 pk;
          #pragma unroll
          for (int reg = 0; reg < 4; reg++) pk[reg] = (f16)fmaxf(C[wt][et][reg], 0.f);
          int col = wt*16 + 4*q;
          *(f16x4*)&H[(r << 6) + ((((col >> 3) ^ (r & 7)) << 3) | (col & 7))] = pk;
        }
      }
    } else if (mode == 1){
      int r = wv*16 + n15;
      #pragma unroll
      for (int wt = 0; wt < 3; wt++){
        f16x4 pk;
        #pragma unroll
        for (int reg = 0; reg < 4; reg++){
          float v1 = fmaxf(C[wt][0][reg], 0.f);
          float v2 = fmaxf(C[wt][1][reg], 0.f);
          float dd = v1 - v2; side += dd * dd;
          pk[reg] = (f16)(0.5f * (v1 + v2));
        }
        int col = wt*16 + 4*q;
        *(f16x4*)&H[(r << 6) + ((((col >> 3) ^ (r & 7)) << 3) | (col & 7))] = pk;
      }
    } else if (mode == 2){
      #pragma unroll
      for (int wt = 0; wt < 3; wt++){
        float wa[4] = {wc1r[wt].x, wc1r[wt].y, wc1r[wt].z, wc1r[wt].w};
        #pragma unroll
        for (int reg = 0; reg < 4; reg++)
          ef[wt][reg] = C[wt][0][reg] + aL * wa[reg];
      }
    } else {
      #pragma unroll
      for (int wt = 0; wt < 3; wt++){
        float av[4] = {wcA[wt].x, wcA[wt].y, wcA[wt].z, wcA[wt].w};
        float bv[4] = {wcB[wt].x, wcB[wt].y, wcB[wt].z, wcB[wt].w};
        #pragma unroll
        for (int reg = 0; reg < 4; reg++){
          float v1 = fmaxf(C[wt][0][reg], 0.f);
          float v2 = fmaxf(C[wt][1][reg], 0.f);
          float dd = v1 - v2; side += dd * dd;
          float fe = 0.5f * (v1 + v2);
          outAcc += fe * av[reg] + ef[wt][reg] * bv[reg];
        }
      }
    }
  };

  // ---- prime: load + store step 0 (tile 0, conv 0 on xh1) ----
  pa0 = *(const f16x8*)&xh1[(long)node[0] * 16];
  pa1 = *(const f16x8*)&xh1[(long)node[0] * 16 + 8];
  store_lds(Hb[0]);
  __syncthreads();

  for (int step = 0; step < 2 * ECT; step++){
    int tile = step >> 1, conv = step & 1;
    // prefetch next step's H data
    if (step + 1 < 2 * ECT){
      int nt = (step + 1) >> 1;
      const f16* xh = ((step + 1) & 1) ? xh2 : xh1;
      pa0 = *(const f16x8*)&xh[(long)node[nt] * 16];
      pa1 = *(const f16x8*)&xh[(long)node[nt] * 16 + 8];
    }
    f16* H = Hb[step & 1];
    if (conv == 0){
      aL = actp[gebase + tile * 64 + wv*16 + n15];
      layer(H, 0, e1b0, 1, 0);
      layer(H, 1, e1bh + 0*48, 2, 0);
      layer(H, 2, e1bh + 1*48, 2, 0);
      layer(H, 3, e1bh + 2*48, 2, 0);
      layer(H, 4, e1bh + 3*48, 2, 0);
      layer(H, 5, e1bh + 4*48, 2, 1);
      layer(H, 6, e1bc, 2, 2);
    } else {
      outAcc = 0.f;
      layer(H, 7,  e2b0, 1, 0);
      layer(H, 8,  e2bh + 0*48, 2, 0);
      layer(H, 9,  e2bh + 1*48, 2, 0);
      layer(H, 10, e2bh + 2*48, 2, 0);
      layer(H, 11, e2bh + 3*48, 2, 0);
      layer(H, 12, e2bh + 4*48, 2, 3);
      float v = outAcc;
      v += __shfl_xor(v, 16);
      v += __shfl_xor(v, 32);
      if (lane < 16) outp[gebase + tile * 64 + wv*16 + n15] = v + bc2v;
    }
    if (step + 1 < 2 * ECT) store_lds(Hb[(step + 1) & 1]);
    __syncthreads();
  }

  float sv = side;
  #pragma unroll
  for (int off = 32; off; off >>= 1) sv += __shfl_down(sv, off);
  if (lane == 0) atomicAdd(slacc, sv);
}

// each (edge,channel) counted once per conv: loss = S/(2*48*E)
__global__ void fin_sl(const float* __restrict__ slacc, float* __restrict__ out){
  if (threadIdx.x == 0 && blockIdx.x == 0)
    out[NEDGES] = slacc[0] * (1.0f / 57600000.0f);
}

// ================= launch ==================
extern "C" void kernel_launch(void* const* d_in, const int* in_sizes, int n_in,
                              void* d_out, int out_size, void* d_ws, size_t ws_size,
                              hipStream_t stream)
{
  if (n_in < 25) return;
  if (ws_size < (size_t)WS_NEED_FLOATS * sizeof(float)) return;

  const float* nf  = (const float*)d_in[0];
  const int*   ei  = (const int*)d_in[1];
  const float* ang = (const float*)d_in[2];
  const float* act = (const float*)d_in[4];
  const float* nc1_w0 = (const float*)d_in[5];
  const float* nc1_b0 = (const float*)d_in[6];
  const float* nc1_wh = (const float*)d_in[7];
  const float* nc1_bh = (const float*)d_in[8];
  const float* nc2_w0 = (const float*)d_in[9];
  const float* nc2_b0 = (const float*)d_in[10];
  const float* nc2_wh = (const float*)d_in[11];
  const float* nc2_bh = (const float*)d_in[12];
  const float* e1w0 = (const float*)d_in[13];
  const float* e1b0 = (const float*)d_in[14];
  const float* e1wh = (const float*)d_in[15];
  const float* e1bh = (const float*)d_in[16];
  const float* e1wc = (const float*)d_in[17];
  const float* e1bc = (const float*)d_in[18];
  const float* e2w0 = (const float*)d_in[19];
  const float* e2b0 = (const float*)d_in[20];
  const float* e2wh = (const float*)d_in[21];
  const float* e2bh = (const float*)d_in[22];
  const float* e2wc = (const float*)d_in[23];
  const float* e2bc = (const float*)d_in[24];

  float* ws  = (float*)d_ws;
  float* out = (float*)d_out;

  f16* xh1   = (f16*)(ws + OX1);
  f16* nfh   = (f16*)(ws + ONFH);
  float* actp = ws + ONFH;            // aliases nfh (dead after nc1)
  f16* xh2   = (f16*)(ws + OX2);
  float* outp = ws + OOUTP;
  int* rowptr = (int*)(ws + OROW);
  int* deg    = (int*)(ws + ODEG);
  int* perm   = (int*)(ws + OPERM);
  f16* gf     = (f16*)(ws + OGF);     // aliases deg (dead after scatter_perm)
  float* sl   = ws + OSL;

  const int eb  = (NEDGES + 255) / 256;        // 2344
  const int nb8 = (NNODES * 8 + 255) / 256;    // 3125
  const int pfb = (39936 + 255) / 256;         // 156
  const int cvb = (400000 + 255) / 256;        // 1563

  (void)hipMemsetAsync(deg, 0, (size_t)NNODES * sizeof(int), stream);
  (void)hipMemsetAsync(sl, 0, sizeof(float), stream);

  hipLaunchKernelGGL(cvt_f16, dim3(cvb), dim3(256), 0, stream, nf, nfh, 400000);

  hipLaunchKernelGGL(count_deg, dim3(eb), dim3(256), 0, stream, ei, deg);
  hipLaunchKernelGGL(scan_deg, dim3(1), dim3(1024), 0, stream, deg, rowptr);
  (void)hipMemsetAsync(deg, 0, (size_t)NNODES * sizeof(int), stream);
  hipLaunchKernelGGL(scatter_perm, dim3(eb), dim3(256), 0, stream, ei, rowptr, deg, perm);

  hipLaunchKernelGGL(prep_wfrag, dim3(pfb), dim3(256), 0, stream,
      e1w0, e1wh, e1wc, e2w0, e2wh, gf);

  hipLaunchKernelGGL(nc_csr8h, dim3(nb8), dim3(256), 0, stream,
      nfh, ei, ang, rowptr, perm, nc1_w0, nc1_b0, nc1_wh, nc1_bh, xh1);

  // nfh dead: overwrite region with perm-ordered actions
  hipLaunchKernelGGL(gather_act, dim3(eb), dim3(256), 0, stream, act, perm, actp);

  hipLaunchKernelGGL(nc_csr8h, dim3(nb8), dim3(256), 0, stream,
      xh1, ei, ang, rowptr, perm, nc2_w0, nc2_b0, nc2_wh, nc2_bh, xh2);

  hipLaunchKernelGGL(ec_mfma, dim3(ECNB), dim3(256), 0, stream,
      xh1, xh2, ei, perm, actp, gf,
      e1wc, e1b0, e1bh, e1bc, e2b0, e2bh, e2wc, e2bc,
      outp, sl);

  hipLaunchKernelGGL(scatter_out, dim3(eb), dim3(256), 0, stream, outp, perm, out);
  hipLaunchKernelGGL(fin_sl, dim3(1), dim3(64), 0, stream, sl, out);
}